// Round 1
// baseline (367.480 us; speedup 1.0000x reference)
//
#include <hip/hip_runtime.h>
#include <hip/hip_bf16.h>

// Problem: out[b,s,o] = sum_i x[b,s,i] * (qw[o,i]*scale) + bias[o]
//   => GEMM: M = 4*2048 = 8192, N = 8192, K = 2048, A=[M][K] fp32, W=[N][K] int32.
// Strategy: convert x -> bf16 (RNE), qw -> bf16 (EXACT, ints in [-4,3]),
//           bf16 MFMA GEMM (m97 structure), epilogue applies scale + bias.

#define M_DIM 8192
#define N_DIM 8192
#define K_DIM 2048

typedef __attribute__((ext_vector_type(8))) short bf16x8;
typedef __attribute__((ext_vector_type(4))) float f32x4;

__device__ __forceinline__ ushort f2bf(float f) {
    union { float f; unsigned int u; } v; v.f = f;
    unsigned int u = v.u;
    // round-to-nearest-even
    return (ushort)((u + 0x7fffu + ((u >> 16) & 1u)) >> 16);
}

__global__ void cvt_x_kernel(const float* __restrict__ x, ushort* __restrict__ o, int n4) {
    int i = blockIdx.x * blockDim.x + threadIdx.x;
    if (i < n4) {
        const float4 v = reinterpret_cast<const float4*>(x)[i];
        ushort4 r;
        r.x = f2bf(v.x); r.y = f2bf(v.y); r.z = f2bf(v.z); r.w = f2bf(v.w);
        reinterpret_cast<ushort4*>(o)[i] = r;
    }
}

__global__ void cvt_w_kernel(const int* __restrict__ w, ushort* __restrict__ o, int n4) {
    int i = blockIdx.x * blockDim.x + threadIdx.x;
    if (i < n4) {
        const int4 v = reinterpret_cast<const int4*>(w)[i];
        ushort4 r;
        r.x = f2bf((float)v.x); r.y = f2bf((float)v.y);
        r.z = f2bf((float)v.z); r.w = f2bf((float)v.w);
        reinterpret_cast<ushort4*>(o)[i] = r;
    }
}

// 128x128 tile, BK=32, 4 waves (2x2), 16x16x32 bf16 MFMA. m97 structure.
__global__ __launch_bounds__(256) void gemm_bf16_kernel(
    const ushort* __restrict__ A,   // [M][K] bf16
    const ushort* __restrict__ B,   // [N][K] bf16 (weight, NT layout)
    const float* __restrict__ scale_p,
    const float* __restrict__ bias,
    float* __restrict__ C)          // [M][N] fp32
{
    __shared__ __align__(16) ushort lA[128 * 32];
    __shared__ __align__(16) ushort lB[128 * 32];

    const int tid  = threadIdx.x;
    const int lane = tid & 63;
    const int wave = tid >> 6;
    const int wr = wave >> 1;   // 0..1 wave row
    const int wc = wave & 1;    // 0..1 wave col
    const int bm = blockIdx.y;
    const int bn = blockIdx.x;

    // Staging: tile is 128 rows x 32 bf16 = 512 chunks of 16B; thread t does
    // chunks t and t+256. LDS layout linear => dest = wave_base + lane*16. OK.
    const int srow = tid >> 2;           // 0..63
    const int scol = (tid & 3) * 8;      // 0,8,16,24 (bf16 elems)

    const ushort* gA = A + (size_t)(bm * 128) * K_DIM;
    const ushort* gB = B + (size_t)(bn * 128) * K_DIM;

    f32x4 acc[4][4];
#pragma unroll
    for (int m = 0; m < 4; ++m)
#pragma unroll
        for (int n = 0; n < 4; ++n)
            acc[m][n] = (f32x4){0.f, 0.f, 0.f, 0.f};

    const int lr = lane & 15;            // fragment row/col within 16
    const int kb = (lane >> 4) * 8;      // k sub-offset (bf16 elems)

    for (int k0 = 0; k0 < K_DIM; k0 += 32) {
        __syncthreads();   // prior iteration's ds_reads done before overwrite
        __builtin_amdgcn_global_load_lds(
            (const __attribute__((address_space(1))) unsigned int*)(gA + (size_t)srow * K_DIM + k0 + scol),
            (__attribute__((address_space(3))) unsigned int*)(&lA[tid * 8]), 16, 0, 0);
        __builtin_amdgcn_global_load_lds(
            (const __attribute__((address_space(1))) unsigned int*)(gA + (size_t)(srow + 64) * K_DIM + k0 + scol),
            (__attribute__((address_space(3))) unsigned int*)(&lA[tid * 8 + 2048]), 16, 0, 0);
        __builtin_amdgcn_global_load_lds(
            (const __attribute__((address_space(1))) unsigned int*)(gB + (size_t)srow * K_DIM + k0 + scol),
            (__attribute__((address_space(3))) unsigned int*)(&lB[tid * 8]), 16, 0, 0);
        __builtin_amdgcn_global_load_lds(
            (const __attribute__((address_space(1))) unsigned int*)(gB + (size_t)(srow + 64) * K_DIM + k0 + scol),
            (__attribute__((address_space(3))) unsigned int*)(&lB[tid * 8 + 2048]), 16, 0, 0);
        __syncthreads();   // compiler drains vmcnt(0) before barrier

        bf16x8 af[4], bfr[4];
#pragma unroll
        for (int m = 0; m < 4; ++m)
            af[m] = *reinterpret_cast<const bf16x8*>(&lA[(wr * 64 + m * 16 + lr) * 32 + kb]);
#pragma unroll
        for (int n = 0; n < 4; ++n)
            bfr[n] = *reinterpret_cast<const bf16x8*>(&lB[(wc * 64 + n * 16 + lr) * 32 + kb]);

#pragma unroll
        for (int m = 0; m < 4; ++m)
#pragma unroll
            for (int n = 0; n < 4; ++n)
                acc[m][n] = __builtin_amdgcn_mfma_f32_16x16x32_bf16(af[m], bfr[n], acc[m][n], 0, 0, 0);
    }

    // Epilogue: C/D layout (m89): col = lane&15, row = (lane>>4)*4 + j
    const float s = scale_p[0];
#pragma unroll
    for (int n = 0; n < 4; ++n) {
        const int col = bn * 128 + wc * 64 + n * 16 + lr;
        const float bb = bias[col];
#pragma unroll
        for (int m = 0; m < 4; ++m) {
            const int row0 = bm * 128 + wr * 64 + m * 16 + (lane >> 4) * 4;
#pragma unroll
            for (int j = 0; j < 4; ++j)
                C[(size_t)(row0 + j) * N_DIM + col] = acc[m][n][j] * s + bb;
        }
    }
}

// Correctness-insurance fallback if ws_size < 64 MiB (slow, should not trigger).
__global__ void naive_fallback(const float* __restrict__ x, const int* __restrict__ w,
                               const float* __restrict__ scale, const float* __restrict__ bias,
                               float* __restrict__ out) {
    size_t i = (size_t)blockIdx.x * blockDim.x + threadIdx.x;
    int m = (int)(i / N_DIM);
    int n = (int)(i % N_DIM);
    const float* xr = x + (size_t)m * K_DIM;
    const int*   wrw = w + (size_t)n * K_DIM;
    float acc = 0.f;
    for (int k = 0; k < K_DIM; ++k) acc += xr[k] * (float)wrw[k];
    out[i] = acc * scale[0] + bias[n];
}

extern "C" void kernel_launch(void* const* d_in, const int* in_sizes, int n_in,
                              void* d_out, int out_size, void* d_ws, size_t ws_size,
                              hipStream_t stream) {
    const float* x     = (const float*)d_in[0];
    const int*   qw    = (const int*)d_in[1];
    const float* scale = (const float*)d_in[2];
    const float* bias  = (const float*)d_in[3];
    float* out = (float*)d_out;

    const size_t elems = (size_t)M_DIM * K_DIM;          // 16,777,216 (same for x and w)
    const size_t need  = elems * 2u * sizeof(ushort);    // 64 MiB bf16 scratch

    if (ws_size >= need) {
        ushort* xb = (ushort*)d_ws;
        ushort* wb = xb + elems;
        const int n4 = (int)(elems / 4);                 // 4,194,304
        cvt_x_kernel<<<n4 / 256, 256, 0, stream>>>(x, xb, n4);
        cvt_w_kernel<<<n4 / 256, 256, 0, stream>>>(qw, wb, n4);
        dim3 grid(N_DIM / 128, M_DIM / 128);
        gemm_bf16_kernel<<<grid, 256, 0, stream>>>(xb, wb, scale, bias, out);
    } else {
        const size_t total = (size_t)M_DIM * N_DIM;
        naive_fallback<<<(int)(total / 256), 256, 0, stream>>>(x, qw, scale, bias, out);
    }
}

// Round 2
// 305.694 us; speedup vs baseline: 1.2021x; 1.2021x over previous
//
#include <hip/hip_runtime.h>
#include <hip/hip_bf16.h>

// out[b,s,o] = sum_i x[b,s,i] * (qw[o,i]*scale) + bias[o]
//   => GEMM: M=8192, N=8192, K=2048. bf16 MFMA, fp32 accumulate.
// R2 structure: 256x256 tile, 8 waves (2Mx4N), BK=32, ring-4 LDS K-tile
// buffers staged 3 ahead (counted vmcnt(8), raw s_barrier — no vmcnt(0)
// drain in main loop), XOR bank swizzle (granule ^= (row>>1)&3) applied
// as pre-swizzled global source + swizzled ds_read (rule 21), setprio
// around the MFMA cluster (T5).

#define M_DIM 8192
#define N_DIM 8192
#define K_DIM 2048
#define NT    (K_DIM / 32)   // 64 K-tiles

typedef __attribute__((ext_vector_type(8))) short bf16x8;
typedef __attribute__((ext_vector_type(4))) float f32x4;

__device__ __forceinline__ ushort f2bf(float f) {
    union { float f; unsigned int u; } v; v.f = f;
    unsigned int u = v.u;
    return (ushort)((u + 0x7fffu + ((u >> 16) & 1u)) >> 16);  // RNE
}

__global__ void cvt_x_kernel(const float* __restrict__ x, ushort* __restrict__ o, int n4) {
    int i = blockIdx.x * blockDim.x + threadIdx.x;
    if (i < n4) {
        const float4 v = reinterpret_cast<const float4*>(x)[i];
        ushort4 r;
        r.x = f2bf(v.x); r.y = f2bf(v.y); r.z = f2bf(v.z); r.w = f2bf(v.w);
        reinterpret_cast<ushort4*>(o)[i] = r;
    }
}

__global__ void cvt_w_kernel(const int* __restrict__ w, ushort* __restrict__ o, int n4) {
    int i = blockIdx.x * blockDim.x + threadIdx.x;
    if (i < n4) {
        const int4 v = reinterpret_cast<const int4*>(w)[i];
        ushort4 r;
        r.x = f2bf((float)v.x); r.y = f2bf((float)v.y);
        r.z = f2bf((float)v.z); r.w = f2bf((float)v.w);
        reinterpret_cast<ushort4*>(o)[i] = r;
    }
}

// 256x256 tile, BK=32, 512 threads (8 waves: 2M x 4N), 16x16x32 bf16 MFMA.
// LDS: 4 ring buffers x (A,B) x 256x32 bf16 = 128 KiB -> 1 block/CU.
// LDS row = 64 B (32 bf16). Swizzle: 16B-granule' = granule ^ ((row>>1)&3).
//   - stage: linear LDS dest (base + tid*16), global src pre-swizzled.
//   - read:  byte = row*64 + ((g0 ^ ((row>>1)&3))<<4); (row>>1)&3 == (lane>>1)&3.
// Pipeline: prologue stages tiles 0..2; iter t stages t+3; end-of-t waits
// vmcnt(8) (= loads of t+2,t+3 allowed in flight; in-order retire drains
// t+1's 4 loads) then raw s_barrier. Tail: vmcnt(4) at t=NT-3, vmcnt(0) at NT-2.
__global__ __launch_bounds__(512, 2) void gemm_bf16_kernel(
    const ushort* __restrict__ A,   // [M][K] bf16
    const ushort* __restrict__ B,   // [N][K] bf16
    const float* __restrict__ scale_p,
    const float* __restrict__ bias,
    float* __restrict__ C)          // [M][N] fp32
{
    __shared__ __align__(16) ushort lds[4][2][8192];   // [buf][A/B][256*32]

    const int tid  = threadIdx.x;
    const int lane = tid & 63;
    const int wave = tid >> 6;
    const int wr = wave >> 2;        // 0..1  (M half: 128 rows)
    const int wc = wave & 3;         // 0..3  (N quarter: 64 cols)
    const int bm = blockIdx.y;
    const int bn = blockIdx.x;

    const ushort* gA = A + (size_t)(bm * 256) * K_DIM;
    const ushort* gB = B + (size_t)(bn * 256) * K_DIM;

    // Stage addressing: thread t fills LDS linear bytes [t*16, t*16+16) (row
    // r=t>>2, slot t&3) for R=0 and +8192 B (row r+128) for R=1. The data that
    // belongs in slot s at row r is global granule s ^ ((r>>1)&3); for both R,
    // (r>>1)&3 == (t>>3)&3.
    const int sr = tid >> 2;                       // 0..127
    const int sg = (tid & 3) ^ ((tid >> 3) & 3);   // pre-swizzled source granule
    const ushort* sA0 = gA + (size_t)sr * K_DIM + sg * 8;
    const ushort* sA1 = gA + (size_t)(sr + 128) * K_DIM + sg * 8;
    const ushort* sB0 = gB + (size_t)sr * K_DIM + sg * 8;
    const ushort* sB1 = gB + (size_t)(sr + 128) * K_DIM + sg * 8;

#define STAGE(kt) do {                                                                     \
    const int b_ = (kt) & 3; const int k0_ = (kt) * 32;                                    \
    __builtin_amdgcn_global_load_lds(                                                      \
        (const __attribute__((address_space(1))) unsigned int*)(sA0 + k0_),                \
        (__attribute__((address_space(3))) unsigned int*)(&lds[b_][0][tid * 8]), 16, 0, 0);\
    __builtin_amdgcn_global_load_lds(                                                      \
        (const __attribute__((address_space(1))) unsigned int*)(sA1 + k0_),                \
        (__attribute__((address_space(3))) unsigned int*)(&lds[b_][0][tid * 8 + 4096]), 16, 0, 0);\
    __builtin_amdgcn_global_load_lds(                                                      \
        (const __attribute__((address_space(1))) unsigned int*)(sB0 + k0_),                \
        (__attribute__((address_space(3))) unsigned int*)(&lds[b_][1][tid * 8]), 16, 0, 0);\
    __builtin_amdgcn_global_load_lds(                                                      \
        (const __attribute__((address_space(1))) unsigned int*)(sB1 + k0_),                \
        (__attribute__((address_space(3))) unsigned int*)(&lds[b_][1][tid * 8 + 4096]), 16, 0, 0);\
  } while (0)

    f32x4 acc[8][4];
#pragma unroll
    for (int m = 0; m < 8; ++m)
#pragma unroll
        for (int n = 0; n < 4; ++n)
            acc[m][n] = (f32x4){0.f, 0.f, 0.f, 0.f};

    const int lr   = lane & 15;
    const int swzC = ((lane >> 4) ^ ((lane >> 1) & 3)) << 4;   // swizzled granule byte
    const int offA = (wr * 128 + lr) * 64 + swzC;  // + m*1024 per M-frag
    const int offB = (wc * 64  + lr) * 64 + swzC;  // + n*1024 per N-frag

    // ---- prologue: fill 3 tiles of the ring ----
    STAGE(0); STAGE(1); STAGE(2);
    asm volatile("s_waitcnt vmcnt(8)" ::: "memory");   // drain tile 0 (8 newer stay)
    __builtin_amdgcn_s_barrier();
    asm volatile("" ::: "memory");

#pragma unroll 1
    for (int t = 0; t < NT; ++t) {
        if (t + 3 < NT) STAGE(t + 3);

        const char* baseA = (const char*)&lds[t & 3][0][0];
        const char* baseB = (const char*)&lds[t & 3][1][0];
        bf16x8 af[8], bfr[4];
#pragma unroll
        for (int m = 0; m < 8; ++m)
            af[m] = *(const bf16x8*)(baseA + offA + m * 1024);
#pragma unroll
        for (int n = 0; n < 4; ++n)
            bfr[n] = *(const bf16x8*)(baseB + offB + n * 1024);

        __builtin_amdgcn_s_setprio(1);
#pragma unroll
        for (int m = 0; m < 8; ++m)
#pragma unroll
            for (int n = 0; n < 4; ++n)
                acc[m][n] = __builtin_amdgcn_mfma_f32_16x16x32_bf16(af[m], bfr[n], acc[m][n], 0, 0, 0);
        __builtin_amdgcn_s_setprio(0);

        if (t + 1 < NT) {
            if (t + 3 < NT)      asm volatile("s_waitcnt vmcnt(8)" ::: "memory"); // drain t+1
            else if (t + 2 < NT) asm volatile("s_waitcnt vmcnt(4)" ::: "memory"); // tail
            else                 asm volatile("s_waitcnt vmcnt(0)" ::: "memory"); // tail
            __builtin_amdgcn_s_barrier();
            asm volatile("" ::: "memory");
        }
    }
#undef STAGE

    // Epilogue: C/D layout col = lane&15, row = (lane>>4)*4 + j  (verified R1)
    const float s = scale_p[0];
#pragma unroll
    for (int n = 0; n < 4; ++n) {
        const int col = bn * 256 + wc * 64 + n * 16 + lr;
        const float bb = bias[col];
#pragma unroll
        for (int m = 0; m < 8; ++m) {
            const int row0 = bm * 256 + wr * 128 + m * 16 + (lane >> 4) * 4;
#pragma unroll
            for (int j = 0; j < 4; ++j)
                C[(size_t)(row0 + j) * N_DIM + col] = acc[m][n][j] * s + bb;
        }
    }
}

// Correctness-insurance fallback if ws_size < 64 MiB (should not trigger).
__global__ void naive_fallback(const float* __restrict__ x, const int* __restrict__ w,
                               const float* __restrict__ scale, const float* __restrict__ bias,
                               float* __restrict__ out) {
    size_t i = (size_t)blockIdx.x * blockDim.x + threadIdx.x;
    int m = (int)(i / N_DIM);
    int n = (int)(i % N_DIM);
    const float* xr = x + (size_t)m * K_DIM;
    const int*   wrw = w + (size_t)n * K_DIM;
    float acc = 0.f;
    for (int k = 0; k < K_DIM; ++k) acc += xr[k] * (float)wrw[k];
    out[i] = acc * scale[0] + bias[n];
}

extern "C" void kernel_launch(void* const* d_in, const int* in_sizes, int n_in,
                              void* d_out, int out_size, void* d_ws, size_t ws_size,
                              hipStream_t stream) {
    const float* x     = (const float*)d_in[0];
    const int*   qw    = (const int*)d_in[1];
    const float* scale = (const float*)d_in[2];
    const float* bias  = (const float*)d_in[3];
    float* out = (float*)d_out;

    const size_t elems = (size_t)M_DIM * K_DIM;          // 16,777,216
    const size_t need  = elems * 2u * sizeof(ushort);    // 64 MiB

    if (ws_size >= need) {
        ushort* xb = (ushort*)d_ws;
        ushort* wb = xb + elems;
        const int n4 = (int)(elems / 4);
        cvt_x_kernel<<<n4 / 256, 256, 0, stream>>>(x, xb, n4);
        cvt_w_kernel<<<n4 / 256, 256, 0, stream>>>(qw, wb, n4);
        dim3 grid(N_DIM / 256, M_DIM / 256);
        gemm_bf16_kernel<<<grid, 512, 0, stream>>>(xb, wb, scale, bias, out);
    } else {
        const size_t total = (size_t)M_DIM * N_DIM;
        naive_fallback<<<(int)(total / 256), 256, 0, stream>>>(x, qw, scale, bias, out);
    }
}

// Round 3
// 284.156 us; speedup vs baseline: 1.2932x; 1.0758x over previous
//
#include <hip/hip_runtime.h>
#include <hip/hip_bf16.h>

// out = x @ (qw*scale)^T + b  => GEMM M=8192, N=8192, K=2048, bf16 MFMA.
// R3: m201-style 8-phase schedule. 256x256 tile, 8 waves (2Mx4N), BK=64
// (2 k-halves of 32), 2 LDS dbufs. Per phase: stage 1 piece (16KiB) ->
// [even: vmcnt(10)+barrier] -> ds_read subtile -> 16 MFMA -> barrier.
// Counted vmcnt only (10 steady; 10/8/4/0 tail). Swizzle from R2 (0 conflicts).

#define M_DIM 8192
#define N_DIM 8192
#define K_DIM 2048
#define NT    (K_DIM / 64)   // 32 K-tiles (BK=64), 2 per iteration

typedef __attribute__((ext_vector_type(8))) short bf16x8;
typedef __attribute__((ext_vector_type(4))) float f32x4;

__device__ __forceinline__ ushort f2bf(float f) {
    union { float f; unsigned int u; } v; v.f = f;
    unsigned int u = v.u;
    return (ushort)((u + 0x7fffu + ((u >> 16) & 1u)) >> 16);  // RNE
}

__global__ void cvt_x_kernel(const float* __restrict__ x, ushort* __restrict__ o, int n4) {
    int i = blockIdx.x * blockDim.x + threadIdx.x;
    if (i < n4) {
        const float4 v = reinterpret_cast<const float4*>(x)[i];
        ushort4 r;
        r.x = f2bf(v.x); r.y = f2bf(v.y); r.z = f2bf(v.z); r.w = f2bf(v.w);
        reinterpret_cast<ushort4*>(o)[i] = r;
    }
}

__global__ void cvt_w_kernel(const int* __restrict__ w, ushort* __restrict__ o, int n4) {
    int i = blockIdx.x * blockDim.x + threadIdx.x;
    if (i < n4) {
        const int4 v = reinterpret_cast<const int4*>(w)[i];
        ushort4 r;
        r.x = f2bf((float)v.x); r.y = f2bf((float)v.y);
        r.z = f2bf((float)v.z); r.w = f2bf((float)v.w);
        reinterpret_cast<ushort4*>(o)[i] = r;
    }
}

// Piece = [256 rows][32 k-cols] bf16 = 16 KiB. lds[buf][op(A=0,B=1)][kh][8192].
// Schedule per iteration (tiles t=2i in buf0, t+1 in buf1):
//  p0 E buf0 kh0 mh0 | stage (1,A,1)<-t+1    p4 E buf1 kh0 mh0 | stage (0,A,1)<-t+2
//  p1 O buf0 kh0 mh1 | stage (1,B,1)<-t+1    p5 O buf1 kh0 mh1 | stage (0,B,1)<-t+2
//  p2 E buf0 kh1 mh0 | stage (0,A,0)<-t+2    p6 E buf1 kh1 mh0 | stage (1,A,0)<-t+3
//  p3 O buf0 kh1 mh1 | stage (0,B,0)<-t+2    p7 O buf1 kh1 mh1 | stage (1,B,0)<-t+3
// Every piece staged exactly 6 phases before first read; every stage target
// last read >=1 barrier earlier. vmcnt(10) at even phases drains exactly the
// two pieces (4 loads) needed by that phase's k-half.
__global__ __launch_bounds__(512, 2) void gemm_bf16_kernel(
    const ushort* __restrict__ A,   // [M][K] bf16
    const ushort* __restrict__ B,   // [N][K] bf16
    const float* __restrict__ scale_p,
    const float* __restrict__ bias,
    float* __restrict__ C)          // [M][N] fp32
{
    __shared__ __align__(16) ushort lds[2][2][2][8192];

    const int tid  = threadIdx.x;
    const int lane = tid & 63;
    const int wave = tid >> 6;
    const int wr = wave >> 2;        // 0..1 (128-row M half)
    const int wc = wave & 3;         // 0..3 (64-col N quarter)
    const int bm = blockIdx.y;
    const int bn = blockIdx.x;

    const ushort* gA = A + (size_t)(bm * 256) * K_DIM;
    const ushort* gB = B + (size_t)(bn * 256) * K_DIM;

    // Staging (per piece, 2 loads/thread): load0 -> rows 0..127 (dest tid*16B),
    // load1 -> rows 128..255 (dest +8KiB). Source granule pre-swizzled
    // (sg = slot ^ ((row>>1)&3)), linear LDS dest (rule 21).
    const int sr = tid >> 2;                       // 0..127
    const int sg = (tid & 3) ^ ((tid >> 3) & 3);
    const ushort* sA0 = gA + (size_t)sr * K_DIM + sg * 8;
    const ushort* sA1 = gA + (size_t)(sr + 128) * K_DIM + sg * 8;
    const ushort* sB0 = gB + (size_t)sr * K_DIM + sg * 8;
    const ushort* sB1 = gB + (size_t)(sr + 128) * K_DIM + sg * 8;

#define GLDS(src, dst) __builtin_amdgcn_global_load_lds( \
    (const __attribute__((address_space(1))) unsigned int*)(src), \
    (__attribute__((address_space(3))) unsigned int*)(dst), 16, 0, 0)

#define STAGE_P(buf, op, kh, kt) do { \
    const int _c = (kt) * 64 + (kh) * 32; \
    GLDS(((op) ? sB0 : sA0) + _c, &lds[buf][op][kh][tid * 8]); \
    GLDS(((op) ? sB1 : sA1) + _c, &lds[buf][op][kh][tid * 8 + 4096]); \
} while (0)

    f32x4 acc[8][4];
#pragma unroll
    for (int m = 0; m < 8; ++m)
#pragma unroll
        for (int n = 0; n < 4; ++n)
            acc[m][n] = (f32x4){0.f, 0.f, 0.f, 0.f};

    const int lr   = lane & 15;
    const int swzC = ((lane >> 4) ^ ((lane >> 1) & 3)) << 4;
    const int offA = (wr * 128 + lr) * 64 + swzC;   // + mh*4096 + m*1024
    const int offB = (wc * 64  + lr) * 64 + swzC;   // + n*1024

    bf16x8 af[4], bfr[4];

#define DS_AF(buf, kh, mh) do { \
    const char* _p = (const char*)&lds[buf][0][kh][0] + offA + (mh) * 4096; \
    af[0] = *(const bf16x8*)(_p);        af[1] = *(const bf16x8*)(_p + 1024); \
    af[2] = *(const bf16x8*)(_p + 2048); af[3] = *(const bf16x8*)(_p + 3072); \
} while (0)

#define DS_BF(buf, kh) do { \
    const char* _p = (const char*)&lds[buf][1][kh][0] + offB; \
    bfr[0] = *(const bf16x8*)(_p);        bfr[1] = *(const bf16x8*)(_p + 1024); \
    bfr[2] = *(const bf16x8*)(_p + 2048); bfr[3] = *(const bf16x8*)(_p + 3072); \
} while (0)

#define MFMA16(mh) do { \
    _Pragma("unroll") \
    for (int _m = 0; _m < 4; ++_m) \
        _Pragma("unroll") \
        for (int _n = 0; _n < 4; ++_n) \
            acc[(mh) * 4 + _m][_n] = __builtin_amdgcn_mfma_f32_16x16x32_bf16( \
                af[_m], bfr[_n], acc[(mh) * 4 + _m][_n], 0, 0, 0); \
} while (0)

#define BARRIER() do { __builtin_amdgcn_s_barrier(); asm volatile("" ::: "memory"); } while (0)

#define PH_EVEN(buf, kh, STG, VM) do { \
    STG; \
    asm volatile("s_waitcnt vmcnt(" #VM ")" ::: "memory"); \
    BARRIER(); \
    DS_AF(buf, kh, 0); DS_BF(buf, kh); \
    __builtin_amdgcn_s_setprio(1); MFMA16(0); __builtin_amdgcn_s_setprio(0); \
    BARRIER(); \
} while (0)

#define PH_ODD(buf, kh, STG) do { \
    DS_AF(buf, kh, 1); \
    STG; \
    __builtin_amdgcn_s_setprio(1); MFMA16(1); __builtin_amdgcn_s_setprio(0); \
    BARRIER(); \
} while (0)

    // Prologue: tile0 (4 pieces) + tile1 kh0 (2 pieces) = 12 loads in flight.
    STAGE_P(0, 0, 0, 0); STAGE_P(0, 1, 0, 0);
    STAGE_P(0, 0, 1, 0); STAGE_P(0, 1, 1, 0);
    STAGE_P(1, 0, 0, 1); STAGE_P(1, 1, 0, 1);

#pragma unroll 1
    for (int i = 0; i < NT / 2 - 1; ++i) {
        const int t = 2 * i;
        PH_EVEN(0, 0, STAGE_P(1, 0, 1, t + 1), 10);
        PH_ODD (0, 0, STAGE_P(1, 1, 1, t + 1));
        PH_EVEN(0, 1, STAGE_P(0, 0, 0, t + 2), 10);
        PH_ODD (0, 1, STAGE_P(0, 1, 0, t + 2));
        PH_EVEN(1, 0, STAGE_P(0, 0, 1, t + 2), 10);
        PH_ODD (1, 0, STAGE_P(0, 1, 1, t + 2));
        PH_EVEN(1, 1, STAGE_P(1, 0, 0, t + 3), 10);
        PH_ODD (1, 1, STAGE_P(1, 1, 0, t + 3));
    }
    {   // Peel: t = NT-2. p0/p1 still stage tile NT-1's kh1; tail waits 10/8/4/0.
        const int t = NT - 2;
        PH_EVEN(0, 0, STAGE_P(1, 0, 1, t + 1), 10);
        PH_ODD (0, 0, STAGE_P(1, 1, 1, t + 1));
        PH_EVEN(0, 1, (void)0, 8);
        PH_ODD (0, 1, (void)0);
        PH_EVEN(1, 0, (void)0, 4);
        PH_ODD (1, 0, (void)0);
        PH_EVEN(1, 1, (void)0, 0);
        PH_ODD (1, 1, (void)0);
    }

#undef PH_ODD
#undef PH_EVEN
#undef BARRIER
#undef MFMA16
#undef DS_BF
#undef DS_AF
#undef STAGE_P
#undef GLDS

    // Epilogue: C/D layout col = lane&15, row = (lane>>4)*4 + j (verified R1/R2)
    const float s = scale_p[0];
#pragma unroll
    for (int n = 0; n < 4; ++n) {
        const int col = bn * 256 + wc * 64 + n * 16 + lr;
        const float bb = bias[col];
#pragma unroll
        for (int m = 0; m < 8; ++m) {
            const int row0 = bm * 256 + wr * 128 + m * 16 + (lane >> 4) * 4;
#pragma unroll
            for (int j = 0; j < 4; ++j)
                C[(size_t)(row0 + j) * N_DIM + col] = acc[m][n][j] * s + bb;
        }
    }
}

// Correctness-insurance fallback if ws_size < 64 MiB (should not trigger).
__global__ void naive_fallback(const float* __restrict__ x, const int* __restrict__ w,
                               const float* __restrict__ scale, const float* __restrict__ bias,
                               float* __restrict__ out) {
    size_t i = (size_t)blockIdx.x * blockDim.x + threadIdx.x;
    int m = (int)(i / N_DIM);
    int n = (int)(i % N_DIM);
    const float* xr = x + (size_t)m * K_DIM;
    const int*   wrw = w + (size_t)n * K_DIM;
    float acc = 0.f;
    for (int k = 0; k < K_DIM; ++k) acc += xr[k] * (float)wrw[k];
    out[i] = acc * scale[0] + bias[n];
}

extern "C" void kernel_launch(void* const* d_in, const int* in_sizes, int n_in,
                              void* d_out, int out_size, void* d_ws, size_t ws_size,
                              hipStream_t stream) {
    const float* x     = (const float*)d_in[0];
    const int*   qw    = (const int*)d_in[1];
    const float* scale = (const float*)d_in[2];
    const float* bias  = (const float*)d_in[3];
    float* out = (float*)d_out;

    const size_t elems = (size_t)M_DIM * K_DIM;          // 16,777,216
    const size_t need  = elems * 2u * sizeof(ushort);    // 64 MiB

    if (ws_size >= need) {
        ushort* xb = (ushort*)d_ws;
        ushort* wb = xb + elems;
        const int n4 = (int)(elems / 4);
        cvt_x_kernel<<<n4 / 256, 256, 0, stream>>>(x, xb, n4);
        cvt_w_kernel<<<n4 / 256, 256, 0, stream>>>(qw, wb, n4);
        dim3 grid(N_DIM / 256, M_DIM / 256);
        gemm_bf16_kernel<<<grid, 512, 0, stream>>>(xb, wb, scale, bias, out);
    } else {
        const size_t total = (size_t)M_DIM * N_DIM;
        naive_fallback<<<(int)(total / 256), 256, 0, stream>>>(x, qw, scale, bias, out);
    }
}

// Round 4
// 283.030 us; speedup vs baseline: 1.2984x; 1.0040x over previous
//
#include <hip/hip_runtime.h>
#include <hip/hip_bf16.h>

// out = x @ (qw*scale)^T + b  => GEMM M=8192, N=8192, K=2048, bf16 MFMA.
// R4: m201-faithful 8-phase. Per phase: {ds_read subtile; stage 1 piece;
// [odd: vmcnt(8)]; barrier; 16 MFMA; barrier}. The vmcnt at odd phase p
// drains exactly the 2 pieces phase p+1 reads -> ds_reads always issue
// one full phase after their data's drain (RAW-safe) and before the
// pre-MFMA barrier (latency hidden). Swizzle from R2 (0 conflicts).

#define M_DIM 8192
#define N_DIM 8192
#define K_DIM 2048
#define NT    (K_DIM / 64)   // 32 K-tiles (BK=64), 2 per iteration

typedef __attribute__((ext_vector_type(8))) short bf16x8;
typedef __attribute__((ext_vector_type(4))) float f32x4;

__device__ __forceinline__ ushort f2bf(float f) {
    union { float f; unsigned int u; } v; v.f = f;
    unsigned int u = v.u;
    return (ushort)((u + 0x7fffu + ((u >> 16) & 1u)) >> 16);  // RNE
}

__global__ void cvt_x_kernel(const float* __restrict__ x, ushort* __restrict__ o, int n4) {
    int i = blockIdx.x * blockDim.x + threadIdx.x;
    if (i < n4) {
        const float4 v = reinterpret_cast<const float4*>(x)[i];
        ushort4 r;
        r.x = f2bf(v.x); r.y = f2bf(v.y); r.z = f2bf(v.z); r.w = f2bf(v.w);
        reinterpret_cast<ushort4*>(o)[i] = r;
    }
}

__global__ void cvt_w_kernel(const int* __restrict__ w, ushort* __restrict__ o, int n4) {
    int i = blockIdx.x * blockDim.x + threadIdx.x;
    if (i < n4) {
        const int4 v = reinterpret_cast<const int4*>(w)[i];
        ushort4 r;
        r.x = f2bf((float)v.x); r.y = f2bf((float)v.y);
        r.z = f2bf((float)v.z); r.w = f2bf((float)v.w);
        reinterpret_cast<ushort4*>(o)[i] = r;
    }
}

// Piece = [256 rows][32 k] bf16 = 16 KiB, 2 gload_lds/thread. lds[buf][op][kh].
// Stage map (iteration i, tiles t=2i buf0 / t+1 buf1):
//  p0: (1,A,kh1)<-t+1   p1: (1,B,kh1)<-t+1   p2: (0,A,kh0)<-t+2  p3: (0,B,kh0)<-t+2
//  p4: (0,A,kh1)<-t+2   p5: (0,B,kh1)<-t+2   p6: (1,A,kh0)<-t+3  p7: (1,B,kh0)<-t+3
// Reads: p0/p1 buf0 kh0 (mh0/mh1), p2/p3 buf0 kh1, p4/p5 buf1 kh0, p6/p7 buf1 kh1.
// vmcnt(8) at p1/p3/p5/p7 drains the 2 pieces the next even phase reads
// (12 in flight steady). Tail: 8/4/0/skip. All WAR: stage target's last
// reader finishes >=1 barrier before the stage issues (verified per piece).
__global__ __launch_bounds__(512, 2) void gemm_bf16_kernel(
    const ushort* __restrict__ A,   // [M][K] bf16
    const ushort* __restrict__ B,   // [N][K] bf16
    const float* __restrict__ scale_p,
    const float* __restrict__ bias,
    float* __restrict__ C)          // [M][N] fp32
{
    __shared__ __align__(16) ushort lds[2][2][2][8192];

    const int tid  = threadIdx.x;
    const int lane = tid & 63;
    const int wave = tid >> 6;
    const int wr = wave >> 2;        // 0..1 (128-row M half)
    const int wc = wave & 3;         // 0..3 (64-col N quarter)
    const int bm = blockIdx.y;
    const int bn = blockIdx.x;

    const ushort* gA = A + (size_t)(bm * 256) * K_DIM;
    const ushort* gB = B + (size_t)(bn * 256) * K_DIM;

    const int sr = tid >> 2;                       // 0..127
    const int sg = (tid & 3) ^ ((tid >> 3) & 3);   // pre-swizzled source granule
    const ushort* sA0 = gA + (size_t)sr * K_DIM + sg * 8;
    const ushort* sA1 = gA + (size_t)(sr + 128) * K_DIM + sg * 8;
    const ushort* sB0 = gB + (size_t)sr * K_DIM + sg * 8;
    const ushort* sB1 = gB + (size_t)(sr + 128) * K_DIM + sg * 8;

#define GLDS(src, dst) __builtin_amdgcn_global_load_lds( \
    (const __attribute__((address_space(1))) unsigned int*)(src), \
    (__attribute__((address_space(3))) unsigned int*)(dst), 16, 0, 0)

#define STAGE_P(buf, op, kh, kt) do { \
    const int _c = (kt) * 64 + (kh) * 32; \
    GLDS(((op) ? sB0 : sA0) + _c, &lds[buf][op][kh][tid * 8]); \
    GLDS(((op) ? sB1 : sA1) + _c, &lds[buf][op][kh][tid * 8 + 4096]); \
} while (0)

    f32x4 acc[8][4];
#pragma unroll
    for (int m = 0; m < 8; ++m)
#pragma unroll
        for (int n = 0; n < 4; ++n)
            acc[m][n] = (f32x4){0.f, 0.f, 0.f, 0.f};

    const int lr   = lane & 15;
    const int swzC = ((lane >> 4) ^ ((lane >> 1) & 3)) << 4;
    const int offA = (wr * 128 + lr) * 64 + swzC;   // + mh*4096 + m*1024
    const int offB = (wc * 64  + lr) * 64 + swzC;   // + n*1024

    bf16x8 af[4], bfr[4];

#define DS_AF(buf, kh, mh) do { \
    const char* _p = (const char*)&lds[buf][0][kh][0] + offA + (mh) * 4096; \
    af[0] = *(const bf16x8*)(_p);        af[1] = *(const bf16x8*)(_p + 1024); \
    af[2] = *(const bf16x8*)(_p + 2048); af[3] = *(const bf16x8*)(_p + 3072); \
} while (0)

#define DS_BF(buf, kh) do { \
    const char* _p = (const char*)&lds[buf][1][kh][0] + offB; \
    bfr[0] = *(const bf16x8*)(_p);        bfr[1] = *(const bf16x8*)(_p + 1024); \
    bfr[2] = *(const bf16x8*)(_p + 2048); bfr[3] = *(const bf16x8*)(_p + 3072); \
} while (0)

#define MFMA16(mh) do { \
    _Pragma("unroll") \
    for (int _m = 0; _m < 4; ++_m) \
        _Pragma("unroll") \
        for (int _n = 0; _n < 4; ++_n) \
            acc[(mh) * 4 + _m][_n] = __builtin_amdgcn_mfma_f32_16x16x32_bf16( \
                af[_m], bfr[_n], acc[(mh) * 4 + _m][_n], 0, 0, 0); \
} while (0)

#define BARRIER() do { __builtin_amdgcn_s_barrier(); asm volatile("" ::: "memory"); } while (0)

// Even phase: ds_read (af mh0 + bf), stage, barrier, MFMA, barrier.
#define PH_EVEN(buf, kh, STG) do { \
    DS_AF(buf, kh, 0); DS_BF(buf, kh); \
    STG; \
    BARRIER(); \
    __builtin_amdgcn_s_setprio(1); MFMA16(0); __builtin_amdgcn_s_setprio(0); \
    BARRIER(); \
} while (0)

// Odd phase: ds_read (af mh1, bf reused), stage, vmcnt(N) draining the two
// pieces the NEXT even phase reads, barrier, MFMA, barrier.
#define PH_ODD(buf, kh, STG, VM) do { \
    DS_AF(buf, kh, 1); \
    STG; \
    asm volatile("s_waitcnt vmcnt(" #VM ")" ::: "memory"); \
    BARRIER(); \
    __builtin_amdgcn_s_setprio(1); MFMA16(1); __builtin_amdgcn_s_setprio(0); \
    BARRIER(); \
} while (0)

    // Prologue: 6 pieces (12 loads): tile0 all + tile1 kh0. Then drain the
    // first 2 pieces (buf0 kh0 = p0's data) and sync.
    STAGE_P(0, 0, 0, 0); STAGE_P(0, 1, 0, 0);
    STAGE_P(0, 0, 1, 0); STAGE_P(0, 1, 1, 0);
    STAGE_P(1, 0, 0, 1); STAGE_P(1, 1, 0, 1);
    asm volatile("s_waitcnt vmcnt(8)" ::: "memory");
    BARRIER();

#pragma unroll 1
    for (int i = 0; i < NT / 2 - 1; ++i) {
        const int t = 2 * i;
        PH_EVEN(0, 0, STAGE_P(1, 0, 1, t + 1));
        PH_ODD (0, 0, STAGE_P(1, 1, 1, t + 1), 8);
        PH_EVEN(0, 1, STAGE_P(0, 0, 0, t + 2));
        PH_ODD (0, 1, STAGE_P(0, 1, 0, t + 2), 8);
        PH_EVEN(1, 0, STAGE_P(0, 0, 1, t + 2));
        PH_ODD (1, 0, STAGE_P(0, 1, 1, t + 2), 8);
        PH_EVEN(1, 1, STAGE_P(1, 0, 0, t + 3));
        PH_ODD (1, 1, STAGE_P(1, 1, 0, t + 3), 8);
    }
    {   // Peel: t = NT-2. Only tile NT-1 kh1 still stages; tail vmcnt 8/4/0/skip.
        PH_EVEN(0, 0, STAGE_P(1, 0, 1, NT - 1));
        PH_ODD (0, 0, STAGE_P(1, 1, 1, NT - 1), 8);
        PH_EVEN(0, 1, (void)0);
        PH_ODD (0, 1, (void)0, 4);
        PH_EVEN(1, 0, (void)0);
        PH_ODD (1, 0, (void)0, 0);
        PH_EVEN(1, 1, (void)0);
        {   // p7: no vmcnt needed (nothing in flight), no trailing barrier needed
            DS_AF(1, 1, 1);
            __builtin_amdgcn_s_setprio(1); MFMA16(1); __builtin_amdgcn_s_setprio(0);
        }
    }

#undef PH_ODD
#undef PH_EVEN
#undef BARRIER
#undef MFMA16
#undef DS_BF
#undef DS_AF
#undef STAGE_P
#undef GLDS

    // Epilogue: C/D layout col = lane&15, row = (lane>>4)*4 + j (verified R1-R3)
    const float s = scale_p[0];
#pragma unroll
    for (int n = 0; n < 4; ++n) {
        const int col = bn * 256 + wc * 64 + n * 16 + lr;
        const float bb = bias[col];
#pragma unroll
        for (int m = 0; m < 8; ++m) {
            const int row0 = bm * 256 + wr * 128 + m * 16 + (lane >> 4) * 4;
#pragma unroll
            for (int j = 0; j < 4; ++j)
                C[(size_t)(row0 + j) * N_DIM + col] = acc[m][n][j] * s + bb;
        }
    }
}

// Correctness-insurance fallback if ws_size < 64 MiB (should not trigger).
__global__ void naive_fallback(const float* __restrict__ x, const int* __restrict__ w,
                               const float* __restrict__ scale, const float* __restrict__ bias,
                               float* __restrict__ out) {
    size_t i = (size_t)blockIdx.x * blockDim.x + threadIdx.x;
    int m = (int)(i / N_DIM);
    int n = (int)(i % N_DIM);
    const float* xr = x + (size_t)m * K_DIM;
    const int*   wrw = w + (size_t)n * K_DIM;
    float acc = 0.f;
    for (int k = 0; k < K_DIM; ++k) acc += xr[k] * (float)wrw[k];
    out[i] = acc * scale[0] + bias[n];
}

extern "C" void kernel_launch(void* const* d_in, const int* in_sizes, int n_in,
                              void* d_out, int out_size, void* d_ws, size_t ws_size,
                              hipStream_t stream) {
    const float* x     = (const float*)d_in[0];
    const int*   qw    = (const int*)d_in[1];
    const float* scale = (const float*)d_in[2];
    const float* bias  = (const float*)d_in[3];
    float* out = (float*)d_out;

    const size_t elems = (size_t)M_DIM * K_DIM;          // 16,777,216
    const size_t need  = elems * 2u * sizeof(ushort);    // 64 MiB

    if (ws_size >= need) {
        ushort* xb = (ushort*)d_ws;
        ushort* wb = xb + elems;
        const int n4 = (int)(elems / 4);
        cvt_x_kernel<<<n4 / 256, 256, 0, stream>>>(x, xb, n4);
        cvt_w_kernel<<<n4 / 256, 256, 0, stream>>>(qw, wb, n4);
        dim3 grid(N_DIM / 256, M_DIM / 256);
        gemm_bf16_kernel<<<grid, 512, 0, stream>>>(xb, wb, scale, bias, out);
    } else {
        const size_t total = (size_t)M_DIM * N_DIM;
        naive_fallback<<<(int)(total / 256), 256, 0, stream>>>(x, qw, scale, bias, out);
    }
}